// Round 9
// baseline (79.259 us; speedup 1.0000x reference)
//
#include <hip/hip_runtime.h>
#include <stdint.h>

#define OUT_F 8192
#define IN_F  8192
#define NGRP  1048576            // OUT*IN/GS
#define BATCH 64
#define KC    16                 // split-K chunks
#define KCHUNK (IN_F / KC)       // 512 k per wave
#define NSTEP (KCHUNK / 32)      // 16 steps of k=32

typedef float f32x4 __attribute__((ext_vector_type(4)));
typedef _Float16 half8_t __attribute__((ext_vector_type(8)));

static __device__ __forceinline__ unsigned int pk_fma_f16(unsigned int a, unsigned int b, unsigned int c) {
  unsigned int d;
  asm("v_pk_fma_f16 %0, %1, %2, %3" : "=v"(d) : "v"(a), "v"(b), "v"(c));
  return d;
}
static __device__ __forceinline__ unsigned int pk16(float a, float b) {
  unsigned short ua = __builtin_bit_cast(unsigned short, (_Float16)a);
  unsigned short ub = __builtin_bit_cast(unsigned short, (_Float16)b);
  return (unsigned int)ua | ((unsigned int)ub << 16);
}

// ---- fused pre-pass: x fp32->f16  +  per-2-group {f16x2(s), f16x2(-(64+z)s)} ----
__global__ __launch_bounds__(256) void pre_kernel(const float* __restrict__ x, ushort* __restrict__ xh,
                                                  const float* __restrict__ scale, const float* __restrict__ zero,
                                                  uint32_t* __restrict__ szb) {
  const int b = blockIdx.x;
  if (b < 512) {                      // 512*256 = BATCH*IN_F/4
    const int i = b * 256 + threadIdx.x;
    float4 v = ((const float4*)x)[i];
    ushort4 o;
    o.x = __builtin_bit_cast(unsigned short, (_Float16)v.x);
    o.y = __builtin_bit_cast(unsigned short, (_Float16)v.y);
    o.z = __builtin_bit_cast(unsigned short, (_Float16)v.z);
    o.w = __builtin_bit_cast(unsigned short, (_Float16)v.w);
    ((ushort4*)xh)[i] = o;
  } else {                            // 1024*256 = NGRP/4
    const int i = (b - 512) * 256 + threadIdx.x;
    float4 s = ((const float4*)scale)[i];
    float4 z = ((const float4*)zero)[i];
    uint4 o;
    o.x = pk16(s.x, s.y);
    o.y = pk16(-(64.f + z.x) * s.x, -(64.f + z.y) * s.y);
    o.z = pk16(s.z, s.w);
    o.w = pk16(-(64.f + z.z) * s.z, -(64.f + z.w) * s.w);
    ((uint4*)szb)[i] = o;
  }
}

// ---- main fused dequant + GEMM: barrier-free, LDS-free, per-wave register dataflow ----
// NEW mapping (anti 4MB-stride-alias): grid 1024: r = bid&31 (packed Wq row),
// ccb = (bid>>5)&7 (16 group-cols), kcb = bid>>8; wave wid -> kc = kcb*4+wid.
// Lane: n = lane&15 -> group-col cc = ccb*16+n (32 KB stride between lanes,
// contiguous within lane); k-octet = lane>>4. Hi nibble -> o = r*128+cc, lo -> +4096.
__global__ __launch_bounds__(256, 4) void hqq_gemm_kernel(
    const int* __restrict__ Wq, const uint32_t* __restrict__ szb,
    const ushort* __restrict__ xh, float* __restrict__ part)
{
  const int t    = threadIdx.x;
  const int bid  = blockIdx.x;
  const int r    = bid & 31;
  const int ccb  = (bid >> 5) & 7;
  const int kcb  = bid >> 8;
  const int wid  = t >> 6;
  const int lane = t & 63;
  const int n    = lane & 15;
  const int ko   = (lane >> 4) * 8;
  const int kc   = kcb * 4 + wid;
  const int kbase = kc * KCHUNK;
  const int cc   = ccb * 16 + n;

  const int* __restrict__ wql =
      Wq + (size_t)r * NGRP + (size_t)cc * IN_F + kbase + ko;
  const uint8_t* __restrict__ szl =
      (const uint8_t*)szb + ((size_t)cc * IN_F + kbase + ko) * 4;
  const ushort* __restrict__ xl = xh + (size_t)n * IN_F + kbase + ko;

  f32x4 acc[2][4];
  #pragma unroll
  for (int nn = 0; nn < 2; ++nn)
    #pragma unroll
    for (int m = 0; m < 4; ++m) acc[nn][m] = (f32x4){0.f, 0.f, 0.f, 0.f};

  int4    wr[3][2];    // W prefetch ring, depth 3
  uint4   sr[2][2];    // sz ring, depth 2
  half8_t ar[2][4];    // A ring, depth 2 (L2-resident)

#define LDW(set, s)  do {                                             \
    wr[set][0] = *(const int4*)(wql + (size_t)(s) * 32);              \
    wr[set][1] = *(const int4*)(wql + (size_t)(s) * 32 + 4);          \
  } while (0)
#define LDSZ(set, s) do {                                             \
    sr[set][0] = *(const uint4*)(szl + (size_t)(s) * 128);            \
    sr[set][1] = *(const uint4*)(szl + (size_t)(s) * 128 + 16);       \
  } while (0)
#define LDA(set, s)  do { _Pragma("unroll")                           \
    for (int mq = 0; mq < 4; ++mq)                                    \
      ar[set][mq] = *(const half8_t*)(xl + (size_t)mq * (16 * IN_F) + (s) * 32); \
  } while (0)

  // prologue: 3 W-steps, 2 sz/A-steps in flight
  LDW(0, 0); LDSZ(0, 0); LDA(0, 0);
  LDW(1, 1); LDSZ(1, 1); LDA(1, 1);
  LDW(2, 2);

  #pragma unroll
  for (int s = 0; s < NSTEP; ++s) {
    const int p = s & 1;
    const int q = s % 3;

    // dequant lane's 8 ints -> hi/lo B-fragments (f16 magic: 0x5400|(v<<4) == 64+v)
    union { uint4 u; half8_t h; } uh, ul;
    {
      unsigned tt = ((unsigned)wr[q][0].y << 16) | (unsigned)wr[q][0].x;
      uh.u.x = pk_fma_f16((tt & 0x00F000F0u) | 0x54005400u, sr[p][0].x, sr[p][0].y);
      ul.u.x = pk_fma_f16(((tt << 4) & 0x00F000F0u) | 0x54005400u, sr[p][0].x, sr[p][0].y);
    }
    {
      unsigned tt = ((unsigned)wr[q][0].w << 16) | (unsigned)wr[q][0].z;
      uh.u.y = pk_fma_f16((tt & 0x00F000F0u) | 0x54005400u, sr[p][0].z, sr[p][0].w);
      ul.u.y = pk_fma_f16(((tt << 4) & 0x00F000F0u) | 0x54005400u, sr[p][0].z, sr[p][0].w);
    }
    {
      unsigned tt = ((unsigned)wr[q][1].y << 16) | (unsigned)wr[q][1].x;
      uh.u.z = pk_fma_f16((tt & 0x00F000F0u) | 0x54005400u, sr[p][1].x, sr[p][1].y);
      ul.u.z = pk_fma_f16(((tt << 4) & 0x00F000F0u) | 0x54005400u, sr[p][1].x, sr[p][1].y);
    }
    {
      unsigned tt = ((unsigned)wr[q][1].w << 16) | (unsigned)wr[q][1].z;
      uh.u.w = pk_fma_f16((tt & 0x00F000F0u) | 0x54005400u, sr[p][1].z, sr[p][1].w);
      ul.u.w = pk_fma_f16(((tt << 4) & 0x00F000F0u) | 0x54005400u, sr[p][1].z, sr[p][1].w);
    }
    const half8_t bhi = uh.h;
    const half8_t blo = ul.h;

    // refill consumed W/sz slots early (issue before MFMA block)
    if (s + 3 < NSTEP) LDW(q, s + 3);
    if (s + 2 < NSTEP) LDSZ(p, s + 2);

    #pragma unroll
    for (int mq = 0; mq < 4; ++mq) {
      acc[0][mq] = __builtin_amdgcn_mfma_f32_16x16x32_f16(ar[p][mq], bhi, acc[0][mq], 0, 0, 0);
      acc[1][mq] = __builtin_amdgcn_mfma_f32_16x16x32_f16(ar[p][mq], blo, acc[1][mq], 0, 0, 0);
    }

    // refill A slot after its last MFMA use
    if (s + 2 < NSTEP) LDA(p, s + 2);
  }
#undef LDW
#undef LDSZ
#undef LDA

  // epilogue: C/D col = lane&15 = n -> o = r*128+cc (hi) / +4096 (lo);
  // row = (lane>>4)*4 + j, m = mq*16 + row
  const int o_hi = r * 128 + cc;
  const int msub = (lane >> 4) * 4;
  float* p0 = part + ((size_t)kc * OUT_F + o_hi) * BATCH + msub;
  float* p1 = part + ((size_t)kc * OUT_F + o_hi + 4096) * BATCH + msub;
  #pragma unroll
  for (int mq = 0; mq < 4; ++mq) {
    *(float4*)(p0 + mq * 16) = (float4){acc[0][mq][0], acc[0][mq][1], acc[0][mq][2], acc[0][mq][3]};
    *(float4*)(p1 + mq * 16) = (float4){acc[1][mq][0], acc[1][mq][1], acc[1][mq][2], acc[1][mq][3]};
  }
}

// ---- split-K reduce + bias + transpose to out[m][o] ----
__global__ __launch_bounds__(256) void reduce_kernel(const float* __restrict__ part,
                                                     const float* __restrict__ bias,
                                                     float* __restrict__ out)
{
  __shared__ float tile[32][65];
  const int ob = blockIdx.x;          // o-range [ob*32, +32)
  const int t  = threadIdx.x;
  {
    const int ol = t >> 3;            // 0..31
    const int mg = t & 7;             // m-octet
    const int o  = ob * 32 + ol;
    const size_t base = (size_t)o * BATCH + mg * 8;
    float s[8] = {0, 0, 0, 0, 0, 0, 0, 0};
    #pragma unroll
    for (int kc = 0; kc < KC; ++kc) {
      const float* p = part + (size_t)kc * OUT_F * BATCH + base;
      float4 a = *(const float4*)p;
      float4 b = *(const float4*)(p + 4);
      s[0] += a.x; s[1] += a.y; s[2] += a.z; s[3] += a.w;
      s[4] += b.x; s[5] += b.y; s[6] += b.z; s[7] += b.w;
    }
    const float bv = bias[o];
    #pragma unroll
    for (int j = 0; j < 8; ++j) tile[ol][mg * 8 + j] = s[j] + bv;
  }
  __syncthreads();
  {
    const int m  = t >> 2;            // 0..63
    const int og = (t & 3) * 8;       // 0..31
    float r[8];
    #pragma unroll
    for (int j = 0; j < 8; ++j) r[j] = tile[og + j][m];
    float* op = out + (size_t)m * OUT_F + ob * 32 + og;
    *(float4*)op       = (float4){r[0], r[1], r[2], r[3]};
    *(float4*)(op + 4) = (float4){r[4], r[5], r[6], r[7]};
  }
}

// ---- correctness fallback (tiny ws), fp32 ----
__global__ void hqq_fallback_kernel(const float* __restrict__ x, const int* __restrict__ Wq,
                                    const float* __restrict__ scale, const float* __restrict__ zero,
                                    const float* __restrict__ bias, float* __restrict__ out)
{
  int idx = blockIdx.x * blockDim.x + threadIdx.x;
  int b = idx >> 13;
  int o = idx & 8191;
  int g = o >> 7, cc = o & 127;
  int r = g & 31;
  bool hi = (g < 32);
  const int*   wrow = Wq    + (size_t)r  * NGRP + (size_t)cc * IN_F;
  const float* srow = scale + (size_t)cc * IN_F;
  const float* zrow = zero  + (size_t)cc * IN_F;
  const float* xrow = x     + (size_t)b  * IN_F;
  float acc = 0.f;
  for (int k = 0; k < IN_F; ++k) {
    int v = wrow[k];
    float nib = (float)(hi ? (v >> 4) : (v & 15));
    acc += xrow[k] * ((nib - zrow[k]) * srow[k]);
  }
  out[idx] = acc + bias[o];
}

extern "C" void kernel_launch(void* const* d_in, const int* in_sizes, int n_in,
                              void* d_out, int out_size, void* d_ws, size_t ws_size,
                              hipStream_t stream) {
  const float* x     = (const float*)d_in[0];
  const int*   Wq    = (const int*)d_in[1];
  const float* scale = (const float*)d_in[2];
  const float* zero  = (const float*)d_in[3];
  const float* bias  = (const float*)d_in[4];
  float* out = (float*)d_out;

  const size_t xh_bytes   = (size_t)BATCH * IN_F * sizeof(ushort);        // 1 MB
  const size_t sz_bytes   = (size_t)NGRP * 4;                             // 4 MB
  const size_t part_bytes = (size_t)KC * BATCH * OUT_F * sizeof(float);   // 32 MB

  if (ws_size >= xh_bytes + sz_bytes + part_bytes) {
    ushort*   xh   = (ushort*)d_ws;
    uint32_t* szb  = (uint32_t*)((char*)d_ws + xh_bytes);
    float*    part = (float*)((char*)d_ws + xh_bytes + sz_bytes);
    pre_kernel<<<1536, 256, 0, stream>>>(x, xh, scale, zero, szb);
    hqq_gemm_kernel<<<128 * 8, 256, 0, stream>>>(Wq, szb, xh, part);
    reduce_kernel<<<OUT_F / 32, 256, 0, stream>>>(part, bias, out);
  } else {
    hqq_fallback_kernel<<<(BATCH * OUT_F) / 256, 256, 0, stream>>>(x, Wq, scale, zero, bias, out);
  }
}

// Round 11
// 55.142 us; speedup vs baseline: 1.4373x; 1.4373x over previous
//
#include <hip/hip_runtime.h>
#include <stdint.h>

#define OUT_F 8192
#define IN_F  8192
#define NGRP  1048576      // OUT*IN/GS
#define BATCH 64
#define KS    4
#define NSTEP ((IN_F / KS) / 128)   // 16

typedef float f32x4 __attribute__((ext_vector_type(4)));
typedef _Float16 half8_t __attribute__((ext_vector_type(8)));

static __device__ __forceinline__ unsigned int pk_fma_f16(unsigned int a, unsigned int b, unsigned int c) {
  unsigned int d;
  asm("v_pk_fma_f16 %0, %1, %2, %3" : "=v"(d) : "v"(a), "v"(b), "v"(c));
  return d;
}
static __device__ __forceinline__ unsigned int pk16(float a, float b) {
  unsigned short ua = __builtin_bit_cast(unsigned short, (_Float16)a);
  unsigned short ub = __builtin_bit_cast(unsigned short, (_Float16)b);
  return (unsigned int)ua | ((unsigned int)ub << 16);
}

#define GLL16(g, l)                                                         \
  __builtin_amdgcn_global_load_lds(                                         \
      (const __attribute__((address_space(1))) void*)(g),                   \
      (__attribute__((address_space(3))) void*)(l), 16, 0, 0)

// ---- fused pre-pass: x fp32->f16  +  per-2-group {f16x2(s), f16x2(-(64+z)s)} ----
__global__ __launch_bounds__(256) void pre_kernel(const float* __restrict__ x, ushort* __restrict__ xh,
                                                  const float* __restrict__ scale, const float* __restrict__ zero,
                                                  uint32_t* __restrict__ szb) {
  const int b = blockIdx.x;
  if (b < 512) {                      // 512*256 = BATCH*IN_F/4
    const int i = b * 256 + threadIdx.x;
    float4 v = ((const float4*)x)[i];
    ushort4 o;
    o.x = __builtin_bit_cast(unsigned short, (_Float16)v.x);
    o.y = __builtin_bit_cast(unsigned short, (_Float16)v.y);
    o.z = __builtin_bit_cast(unsigned short, (_Float16)v.z);
    o.w = __builtin_bit_cast(unsigned short, (_Float16)v.w);
    ((ushort4*)xh)[i] = o;
  } else {                            // 1024*256 = NGRP/4
    const int i = (b - 512) * 256 + threadIdx.x;
    float4 s = ((const float4*)scale)[i];
    float4 z = ((const float4*)zero)[i];
    uint4 o;
    o.x = pk16(s.x, s.y);
    o.y = pk16(-(64.f + z.x) * s.x, -(64.f + z.y) * s.y);
    o.z = pk16(s.z, s.w);
    o.w = pk16(-(64.f + z.z) * s.z, -(64.f + z.w) * s.w);
    ((uint4*)szb)[i] = o;
  }
}

// ---- main fused dequant + GEMM: ALL streams via global_load_lds ----
// grid 1024: ks = bid&3 (2048 k each), gq = (bid>>2)&1 (16 Wq rows), c = bid>>3.
// x  [2][64m][128k] f16, wave-private rows (content-swizzled source) -> no cross-wave race.
// W  [4][16 rows][128 int] raw packed, 16B-slot XOR swizzle (slot^row). QUAD buffer:
//    write (s+2)&3 while readers touch (s-1..s+1)&3 -> race-free with stage-before-barrier.
// sz [4][128k] uint, linear.
// Iter s: stage_x(s+1), stage_wsz(s+2) -> vmcnt(10/7/0) -> s_barrier -> compute(s).
__global__ __launch_bounds__(256, 2) void hqq_gemm_kernel(
    const int* __restrict__ Wq, const uint32_t* __restrict__ szb,
    const ushort* __restrict__ xh, float* __restrict__ part)
{
  __shared__ ushort   xlds[2][64 * 128];   // 16 KB each
  __shared__ unsigned wlds[4][16 * 128];   // 8 KB each (raw packed int32)
  __shared__ unsigned szlds[4][256];       // 1 KB each (512 B valid)

  const int t    = threadIdx.x;
  const int bid  = blockIdx.x;
  const int ks   = bid & 3;
  const int gq   = (bid >> 2) & 1;
  const int c    = bid >> 3;
  const int lane = t & 63;
  const int wid  = t >> 6;
  const int kbase = ks * (IN_F / KS);

  // ---- staging source pointers (pre-swizzled per m173) ----
  // W: LDS(row rt, slot u) holds global slot (u ^ rt); gll j covers rows wid*4+2j..+1
  const int rt0 = wid * 4 + (lane >> 5);
  const int rt1 = rt0 + 2;
  const int* __restrict__ wsrc0 =
      Wq + (size_t)(gq * 16 + rt0) * NGRP + (size_t)c * IN_F + kbase + ((lane & 31) ^ rt0) * 4;
  const int* __restrict__ wsrc1 =
      Wq + (size_t)(gq * 16 + rt1) * NGRP + (size_t)c * IN_F + kbase + ((lane & 31) ^ rt1) * 4;
  const uint8_t* __restrict__ szsrc =
      (const uint8_t*)szb + ((size_t)c * IN_F + kbase) * 4 + lane * 16;

  // frag ids
  const int tr = lane & 15;
  const int l4 = lane >> 4;
  const int am = wid * 16 + tr;

  f32x4 acc_h = {0.f, 0.f, 0.f, 0.f};
  f32x4 acc_l = {0.f, 0.f, 0.f, 0.f};

  // x: 4 gll, wave-private rows (source content-swizzled: LDS[m][b] = x[m][b^((m&7)<<4)])
  auto stage_x = [&](int bi, int s) {
    #pragma unroll
    for (int j = 0; j < 4; ++j) {
      const int m    = wid * 16 + j * 4 + (lane >> 4);
      const int scol = ((lane & 15) * 16) ^ ((m & 7) << 4);
      const ushort* g = xh + (size_t)m * IN_F + kbase + s * 128 + (scol >> 1);
      GLL16(g, &xlds[bi][(wid * 16 + j * 4) * 128]);
    }
  };
  // W + sz: 3 gll
  auto stage_wsz = [&](int bi, int s) {
    GLL16(wsrc0 + (size_t)s * 128, &wlds[bi][(wid * 4) * 128]);
    GLL16(wsrc1 + (size_t)s * 128, &wlds[bi][(wid * 4 + 2) * 128]);
    GLL16(szsrc + (size_t)s * 512, &szlds[bi][0]);   // dup x4 waves, same data, benign
  };

  // prologue: x(0), wsz(0), wsz(1) in flight
  stage_x(0, 0);
  stage_wsz(0, 0);
  stage_wsz(1, 1);

  #pragma unroll 1
  for (int s = 0; s < NSTEP; ++s) {
    if (s + 1 < NSTEP) stage_x((s + 1) & 1, s + 1);
    if (s + 2 < NSTEP) stage_wsz((s + 2) & 3, s + 2);

    // in-order vmcnt: newer-than-needed = wsz(s+1)[3] + x(s+1)[4] + wsz(s+2)[3]
    if (s + 2 < NSTEP)      asm volatile("s_waitcnt vmcnt(10)" ::: "memory");
    else if (s + 1 < NSTEP) asm volatile("s_waitcnt vmcnt(7)" ::: "memory");
    else                    asm volatile("s_waitcnt vmcnt(0)" ::: "memory");
    __builtin_amdgcn_sched_barrier(0);
    __builtin_amdgcn_s_barrier();      // everyone's buf[s] staged
    __builtin_amdgcn_sched_barrier(0);

    const uint8_t* xb = (const uint8_t*)&xlds[s & 1][0];
    const uint8_t* wb = (const uint8_t*)&wlds[s & 3][0];
    const uint8_t* zb = (const uint8_t*)&szlds[s & 3][0];

    #pragma unroll
    for (int kk = 0; kk < 4; ++kk) {
      const int o2 = (kk * 4 + l4) * 2;                 // 16B-slot index (2 per octet)
      uint4 q0 = *(const uint4*)(wb + tr * 512 + ((o2 ^ tr) << 4));
      uint4 q1 = *(const uint4*)(wb + tr * 512 + (((o2 + 1) ^ tr) << 4));
      uint4 sa = *(const uint4*)(zb + kk * 128 + l4 * 32);
      uint4 sb = *(const uint4*)(zb + kk * 128 + l4 * 32 + 16);

      // dequant: f16 magic 0x5400|(v<<4) == 64+v (nibble at mantissa [7:4])
      union { uint4 u; half8_t h; } uh, ul;
      {
        unsigned tt = ((unsigned)q0.y << 16) | (unsigned)q0.x;
        uh.u.x = pk_fma_f16((tt & 0x00F000F0u) | 0x54005400u, sa.x, sa.y);
        ul.u.x = pk_fma_f16(((tt << 4) & 0x00F000F0u) | 0x54005400u, sa.x, sa.y);
      }
      {
        unsigned tt = ((unsigned)q0.w << 16) | (unsigned)q0.z;
        uh.u.y = pk_fma_f16((tt & 0x00F000F0u) | 0x54005400u, sa.z, sa.w);
        ul.u.y = pk_fma_f16(((tt << 4) & 0x00F000F0u) | 0x54005400u, sa.z, sa.w);
      }
      {
        unsigned tt = ((unsigned)q1.y << 16) | (unsigned)q1.x;
        uh.u.z = pk_fma_f16((tt & 0x00F000F0u) | 0x54005400u, sb.x, sb.y);
        ul.u.z = pk_fma_f16(((tt << 4) & 0x00F000F0u) | 0x54005400u, sb.x, sb.y);
      }
      {
        unsigned tt = ((unsigned)q1.w << 16) | (unsigned)q1.z;
        uh.u.w = pk_fma_f16((tt & 0x00F000F0u) | 0x54005400u, sb.z, sb.w);
        ul.u.w = pk_fma_f16(((tt << 4) & 0x00F000F0u) | 0x54005400u, sb.z, sb.w);
      }

      const int colb = (l4 * 8 + kk * 32) * 2;
      half8_t a = *(const half8_t*)(xb + am * 256 + (colb ^ ((am & 7) << 4)));
      acc_h = __builtin_amdgcn_mfma_f32_16x16x32_f16(a, uh.h, acc_h, 0, 0, 0);
      acc_l = __builtin_amdgcn_mfma_f32_16x16x32_f16(a, ul.h, acc_l, 0, 0, 0);
    }
  }

  // epilogue: C/D col = lane&15 -> o, row = (lane>>4)*4 + j -> m
  const int o_hi = (gq * 16 + tr) * 128 + c;
  const int m0   = wid * 16 + l4 * 4;
  float* p_hi = part + ((size_t)ks * OUT_F + o_hi) * BATCH + m0;
  float* p_lo = part + ((size_t)ks * OUT_F + o_hi + 4096) * BATCH + m0;
  *(float4*)p_hi = (float4){acc_h[0], acc_h[1], acc_h[2], acc_h[3]};
  *(float4*)p_lo = (float4){acc_l[0], acc_l[1], acc_l[2], acc_l[3]};
}

// ---- split-K reduce + bias + transpose to out[m][o] ----
__global__ __launch_bounds__(256) void reduce_kernel(const float* __restrict__ part,
                                                     const float* __restrict__ bias,
                                                     float* __restrict__ out)
{
  __shared__ float tile[32][65];
  const int ob = blockIdx.x;          // o-range [ob*32, +32)
  const int t  = threadIdx.x;
  {
    const int ol = t >> 3;            // 0..31
    const int mg = t & 7;             // m-octet
    const int o  = ob * 32 + ol;
    const size_t base = (size_t)o * BATCH + mg * 8;
    float s[8] = {0, 0, 0, 0, 0, 0, 0, 0};
    #pragma unroll
    for (int ks = 0; ks < KS; ++ks) {
      const float* p = part + (size_t)ks * OUT_F * BATCH + base;
      float4 a = *(const float4*)p;
      float4 b = *(const float4*)(p + 4);
      s[0] += a.x; s[1] += a.y; s[2] += a.z; s[3] += a.w;
      s[4] += b.x; s[5] += b.y; s[6] += b.z; s[7] += b.w;
    }
    const float bv = bias[o];
    #pragma unroll
    for (int j = 0; j < 8; ++j) tile[ol][mg * 8 + j] = s[j] + bv;
  }
  __syncthreads();
  {
    const int m  = t >> 2;            // 0..63
    const int og = (t & 3) * 8;       // 0..31
    float r[8];
    #pragma unroll
    for (int j = 0; j < 8; ++j) r[j] = tile[og + j][m];
    float* op = out + (size_t)m * OUT_F + ob * 32 + og;
    *(float4*)op       = (float4){r[0], r[1], r[2], r[3]};
    *(float4*)(op + 4) = (float4){r[4], r[5], r[6], r[7]};
  }
}

// ---- correctness fallback (tiny ws), fp32 ----
__global__ void hqq_fallback_kernel(const float* __restrict__ x, const int* __restrict__ Wq,
                                    const float* __restrict__ scale, const float* __restrict__ zero,
                                    const float* __restrict__ bias, float* __restrict__ out)
{
  int idx = blockIdx.x * blockDim.x + threadIdx.x;
  int b = idx >> 13;
  int o = idx & 8191;
  int g = o >> 7, cc = o & 127;
  int r = g & 31;
  bool hi = (g < 32);
  const int*   wrow = Wq    + (size_t)r  * NGRP + (size_t)cc * IN_F;
  const float* srow = scale + (size_t)cc * IN_F;
  const float* zrow = zero  + (size_t)cc * IN_F;
  const float* xrow = x     + (size_t)b  * IN_F;
  float acc = 0.f;
  for (int k = 0; k < IN_F; ++k) {
    int v = wrow[k];
    float nib = (float)(hi ? (v >> 4) : (v & 15));
    acc += xrow[k] * ((nib - zrow[k]) * srow[k]);
  }
  out[idx] = acc + bias[o];
}

extern "C" void kernel_launch(void* const* d_in, const int* in_sizes, int n_in,
                              void* d_out, int out_size, void* d_ws, size_t ws_size,
                              hipStream_t stream) {
  const float* x     = (const float*)d_in[0];
  const int*   Wq    = (const int*)d_in[1];
  const float* scale = (const float*)d_in[2];
  const float* zero  = (const float*)d_in[3];
  const float* bias  = (const float*)d_in[4];
  float* out = (float*)d_out;

  const size_t xh_bytes   = (size_t)BATCH * IN_F * sizeof(ushort);        // 1 MB
  const size_t sz_bytes   = (size_t)NGRP * 4;                             // 4 MB
  const size_t part_bytes = (size_t)KS * BATCH * OUT_F * sizeof(float);   // 8 MB
  const size_t pad_bytes  = 1024;                                         // sz gll tail overread pad

  if (ws_size >= xh_bytes + sz_bytes + part_bytes + pad_bytes) {
    ushort*   xh   = (ushort*)d_ws;
    uint32_t* szb  = (uint32_t*)((char*)d_ws + xh_bytes);
    float*    part = (float*)((char*)d_ws + xh_bytes + sz_bytes + pad_bytes);
    pre_kernel<<<1536, 256, 0, stream>>>(x, xh, scale, zero, szb);
    hqq_gemm_kernel<<<128 * 2 * KS, 256, 0, stream>>>(Wq, szb, xh, part);
    reduce_kernel<<<OUT_F / 32, 256, 0, stream>>>(part, bias, out);
  } else {
    hqq_fallback_kernel<<<(BATCH * OUT_F) / 256, 256, 0, stream>>>(x, Wq, scale, zero, bias, out);
  }
}